// Round 16
// baseline (77.283 us; speedup 1.0000x reference)
//
#include <hip/hip_runtime.h>
#include <hip/hip_bf16.h>
#include <stdint.h>

typedef _Float16 half8 __attribute__((ext_vector_type(8)));
typedef _Float16 half4 __attribute__((ext_vector_type(4)));
typedef float f32x4 __attribute__((ext_vector_type(4)));
typedef unsigned short ushort8v __attribute__((ext_vector_type(8)));
typedef unsigned short ushort4v __attribute__((ext_vector_type(4)));
typedef unsigned long long u64;

#define N_ROWS 4096
#define DIM 1024
#define KCLS 32
#define MARGIN_F 0.3f

// ---------------- global -> LDS direct staging (16B per lane) ----------------
typedef const __attribute__((address_space(1))) void GASV;
typedef __attribute__((address_space(3))) void LASV;

__device__ __forceinline__ void gload_lds16(const void* g, void* l) {
    __builtin_amdgcn_global_load_lds((GASV*)g, (LASV*)l, 16, 0, 0);
}

// ---------------- prep: sq, f16 convert, prediction argmax ----------------
__global__ __launch_bounds__(256) void prep_kernel(
    const float* __restrict__ inputs, const float* __restrict__ prediction,
    _Float16* __restrict__ xh, float* __restrict__ sq, int* __restrict__ pred_cls)
{
    int wid = threadIdx.x >> 6, lane = threadIdx.x & 63;
    int r = blockIdx.x * 4 + wid;
    const float* row = inputs + (size_t)r * DIM;
    _Float16* hrow = xh + (size_t)r * DIM;
    float s = 0.f;
#pragma unroll
    for (int c = 0; c < 4; ++c) {
        int idx = lane * 4 + c * 256;
        float4 v = *(const float4*)(row + idx);
        s += v.x * v.x + v.y * v.y + v.z * v.z + v.w * v.w;
        half4 h;
        h.x = (_Float16)v.x; h.y = (_Float16)v.y;
        h.z = (_Float16)v.z; h.w = (_Float16)v.w;
        *(half4*)(hrow + idx) = h;
    }
#pragma unroll
    for (int off = 32; off; off >>= 1) s += __shfl_xor(s, off);

    u64 key = 0ull;
    if (lane < KCLS) {
        unsigned b = __float_as_uint(prediction[(size_t)r * KCLS + lane]);
        unsigned u = (b & 0x80000000u) ? ~b : (b | 0x80000000u);
        key = ((u64)u << 32) | (unsigned)(KCLS - 1 - lane);
    }
#pragma unroll
    for (int off = 32; off; off >>= 1) {
        u64 o = __shfl_xor(key, off);
        if (o > key) key = o;
    }
    if (lane == 0) {
        sq[r] = s;
        pred_cls[r] = KCLS - 1 - (int)(key & 0xFFFFFFFFu);
    }
}

// ---------------- f16 MFMA GEMM -> f16 d^2 (flag in sign bit), triangle 128x128 ----------------
// BK=32, 4-buffer, 4-deep counted-vmcnt pipeline: 3 stages (6 loads) stay in flight
// across raw barriers; per-step waits only on its own buffer's 2 loads.
__global__ __launch_bounds__(512) void gemm_kernel(
    const _Float16* __restrict__ X, const float* __restrict__ sq,
    const int* __restrict__ targets,
    unsigned short* __restrict__ out, int mode, int rb0)
{
    __shared__ __align__(16) _Float16 As[4 * 128 * 32];   // 32 KB
    __shared__ __align__(16) _Float16 Bs[4 * 128 * 32];   // 32 KB
    int tid = threadIdx.x;

    int bx, by;
    bool mirror = false;
    if (mode == 0) {
        // bijective XCD swizzle over 528 = 8*66 blocks
        int u = ((int)blockIdx.x & 7) * 66 + ((int)blockIdx.x >> 3);
        int t_ = (int)((sqrtf(8.f * u + 1.f) - 1.f) * 0.5f);
        while ((t_ + 1) * (t_ + 2) / 2 <= u) ++t_;
        while (t_ * (t_ + 1) / 2 > u) --t_;
        by = t_;
        bx = u - t_ * (t_ + 1) / 2;
        mirror = (bx != by);
    } else {
        int nwg = gridDim.x;
        int q = nwg >> 3;
        int swz = ((int)blockIdx.x & 7) * q + ((int)blockIdx.x >> 3);
        int nbx = nwg / 32;
        bx = swz % nbx;
        by = swz / nbx;
    }

    // staging map (BK=32): thread t -> row rs = t>>2 (0..127), slot ss = t&3;
    // source carries inverse 4-slot XOR swizzle.
    int rs = tid >> 2;
    int ss = tid & 3;
    int srcslot = ss ^ (rs & 3);
    const _Float16* gA = X + (size_t)(rb0 + bx * 128 + rs) * DIM + srcslot * 8;
    const _Float16* gB = X + (size_t)(by * 128 + rs) * DIM + srcslot * 8;
    _Float16* lA = As + tid * 8;
    _Float16* lB = Bs + tid * 8;

    int wid = tid >> 6, lane = tid & 63;
    int wr = (wid >> 2) * 64, wc = (wid & 3) * 32;
    int fr = lane & 15, q4 = lane >> 4;

    f32x4 acc[4][2];
#pragma unroll
    for (int m = 0; m < 4; ++m)
#pragma unroll
        for (int n = 0; n < 2; ++n) acc[m][n] = (f32x4){0.f, 0.f, 0.f, 0.f};

    // STAGE(buf, t): 2 loads (1 A + 1 B) for K-step t (k0 = t*32)
    auto STAGE = [&](int buf, int t) {
        int k0 = t * 32;
        gload_lds16(gA + k0, lA + buf * 4096);
        gload_lds16(gB + k0, lB + buf * 4096);
    };
    auto COMPUTE = [&](int buf) {
        const _Float16* Ac = As + buf * 4096;
        const _Float16* Bc = Bs + buf * 4096;
        half8 a[4], b[2];
#pragma unroll
        for (int m = 0; m < 4; ++m) {
            int row = wr + m * 16 + fr;
            int s = q4 ^ (row & 3);
            a[m] = *(const half8*)(Ac + row * 32 + s * 8);
        }
#pragma unroll
        for (int n = 0; n < 2; ++n) {
            int brow = wc + n * 16 + fr;
            int s = q4 ^ (brow & 3);
            b[n] = *(const half8*)(Bc + brow * 32 + s * 8);
        }
        __builtin_amdgcn_s_setprio(1);
#pragma unroll
        for (int m = 0; m < 4; ++m)
#pragma unroll
            for (int n = 0; n < 2; ++n)
                acc[m][n] = __builtin_amdgcn_mfma_f32_16x16x32_f16(a[m], b[n], acc[m][n], 0, 0, 0);
        __builtin_amdgcn_s_setprio(0);
    };

    // prologue: stage K-steps 0..3 (8 loads outstanding)
    STAGE(0, 0); STAGE(1, 1); STAGE(2, 2); STAGE(3, 3);

    // main loop: t = 0..27, 8 outstanding -> wait to 6 retires own 2
    for (int t = 0; t < 28; ++t) {
        asm volatile("s_waitcnt vmcnt(6)" ::: "memory");
        __builtin_amdgcn_s_barrier();
        __builtin_amdgcn_sched_barrier(0);
        COMPUTE(t & 3);
        __builtin_amdgcn_sched_barrier(0);
        __builtin_amdgcn_s_barrier();
        __builtin_amdgcn_sched_barrier(0);
        STAGE(t & 3, t + 4);
    }
    // tail: t = 28 (outstanding 8 -> 6), 29 (6 -> 4), 30 (4 -> 2), 31 (2 -> 0)
    asm volatile("s_waitcnt vmcnt(6)" ::: "memory");
    __builtin_amdgcn_s_barrier();
    __builtin_amdgcn_sched_barrier(0);
    COMPUTE(0);
    __builtin_amdgcn_s_barrier();
    asm volatile("s_waitcnt vmcnt(4)" ::: "memory");
    __builtin_amdgcn_s_barrier();
    __builtin_amdgcn_sched_barrier(0);
    COMPUTE(1);
    __builtin_amdgcn_s_barrier();
    asm volatile("s_waitcnt vmcnt(2)" ::: "memory");
    __builtin_amdgcn_s_barrier();
    __builtin_amdgcn_sched_barrier(0);
    COMPUTE(2);
    __builtin_amdgcn_s_barrier();
    asm volatile("s_waitcnt vmcnt(0)" ::: "memory");
    __builtin_amdgcn_s_barrier();
    __builtin_amdgcn_sched_barrier(0);
    COMPUTE(3);

    // epilogue: d^2 -> f16, same-class flag in sign bit
    int rbase = rb0 + bx * 128 + wr + q4 * 4;
    float sqr_[4][4];
    int trr[4][4];
#pragma unroll
    for (int m = 0; m < 4; ++m)
#pragma unroll
        for (int q = 0; q < 4; ++q) {
            sqr_[m][q] = sq[rbase + m * 16 + q];
            trr[m][q] = targets[rbase + m * 16 + q];
        }

#pragma unroll
    for (int n = 0; n < 2; ++n) {
        int col = by * 128 + wc + n * 16 + fr;
        float sqc = sq[col];
        int tc = targets[col];
#pragma unroll
        for (int m = 0; m < 4; ++m) {
            int row0 = rbase + m * 16;
            ushort4v hv;
#pragma unroll
            for (int q = 0; q < 4; ++q) {
                float d2v = fmaxf(sqr_[m][q] + sqc - 2.f * acc[m][n][q], 1e-12f);
                _Float16 h = (_Float16)d2v;
                unsigned short hb = __builtin_bit_cast(unsigned short, h);
                hb = (unsigned short)(hb | ((trr[m][q] == tc) ? 0x8000u : 0u));
                hv[q] = hb;
                out[(size_t)(row0 + q) * N_ROWS + col] = hb;
            }
            if (mirror)
                *(ushort4v*)&out[(size_t)col * N_ROWS + row0] = hv;
        }
    }
}

// ---------------- per-row selection: u16 scan + u32 prune/bitonic top-k ----------------
// dot[] holds f16 d^2 bits; bit15 = same-class. umin over ALL values = min over
// negatives; umax over ALL = max over positives.
__global__ __launch_bounds__(256) void select_kernel(
    const unsigned short* __restrict__ dot,
    const int* __restrict__ targets, const float* __restrict__ prob,
    const int* __restrict__ pred_cls, const float* __restrict__ thr_p,
    int rb0, float* __restrict__ per_term, int* __restrict__ corr_flag)
{
    __shared__ unsigned Tn[4], Tp[4];
    __shared__ unsigned negCand[64];
    __shared__ unsigned posCand[64];
    __shared__ unsigned cnts[2];
    __shared__ unsigned sN[12], sP[7];
    __shared__ unsigned red[4];
    __shared__ unsigned bcast;

    int t = threadIdx.x, lane = t & 63, w = t >> 6;
    int rloc = blockIdx.x, r = rb0 + rloc;
    const unsigned short* drow = dot + (size_t)rloc * N_ROWS;

    if (t < 64) { negCand[t] = 0xFFFFFFFFu; posCand[t] = 0u; }
    if (t < 2) cnts[t] = 0u;

    unsigned short hb[16];
    unsigned mneg = 0xFFFFFFFFu, mpos = 0u;
    {
        ushort8v v0 = *(const ushort8v*)(drow + t * 8);
        ushort8v v1 = *(const ushort8v*)(drow + 2048 + t * 8);
#pragma unroll
        for (int j = 0; j < 8; ++j) {
            unsigned b = v0[j]; hb[j] = (unsigned short)b;
            mneg = b < mneg ? b : mneg;
            mpos = b > mpos ? b : mpos;
        }
#pragma unroll
        for (int j = 0; j < 8; ++j) {
            unsigned b = v1[j]; hb[8 + j] = (unsigned short)b;
            mneg = b < mneg ? b : mneg;
            mpos = b > mpos ? b : mpos;
        }
    }

    unsigned T3 = 0xFFFFFFFFu, m = mneg;
#pragma unroll
    for (int rd = 0; rd < 3; ++rd) {
        unsigned b = m;
#pragma unroll
        for (int off = 32; off; off >>= 1) {
            unsigned o = __shfl_xor(b, off);
            b = o < b ? o : b;
        }
        T3 = b;
        if (m == b) m = 0xFFFFFFFFu;
    }
    unsigned P2 = 0u, mp = mpos;
#pragma unroll
    for (int rd = 0; rd < 2; ++rd) {
        unsigned b = mp;
#pragma unroll
        for (int off = 32; off; off >>= 1) {
            unsigned o = __shfl_xor(b, off);
            b = o > b ? o : b;
        }
        P2 = b;
        if (mp == b) mp = 0u;
    }
    if (lane == 0) { Tn[w] = T3; Tp[w] = P2; }
    __syncthreads();

    unsigned TnB = Tn[0];
    TnB = Tn[1] > TnB ? Tn[1] : TnB;
    TnB = Tn[2] > TnB ? Tn[2] : TnB;
    TnB = Tn[3] > TnB ? Tn[3] : TnB;
    unsigned TpB = Tp[0];
    TpB = Tp[1] < TpB ? Tp[1] : TpB;
    TpB = Tp[2] < TpB ? Tp[2] : TpB;
    TpB = Tp[3] < TpB ? Tp[3] : TpB;

#pragma unroll
    for (int j = 0; j < 16; ++j) {
        int col = (j < 8) ? (t * 8 + j) : (2048 + t * 8 + (j - 8));
        unsigned b = hb[j];
        if (!(b & 0x8000u) && b <= TnB) {
            unsigned s = atomicAdd(&cnts[0], 1u);
            if (s < 64u) negCand[s] = (b << 16) | (unsigned)col;
        }
        if ((b & 0x8000u) && b >= TpB) {
            unsigned s = atomicAdd(&cnts[1], 1u);
            if (s < 64u) posCand[s] = (b << 16) | (unsigned)(N_ROWS - 1 - col);
        }
    }
    __syncthreads();

    bool fb = (cnts[0] > 64u) || (cnts[1] > 64u);

    if (!fb) {
        if (w == 0) {
            unsigned v = negCand[lane];
#pragma unroll
            for (int k = 2; k <= 64; k <<= 1) {
#pragma unroll
                for (int j = 32; j; j >>= 1) {
                    if (j >= k) continue;
                    unsigned o = __shfl_xor(v, j);
                    bool up = (lane & k) == 0;
                    bool small = (lane & j) == 0;
                    bool keepmin = (small == up);
                    unsigned lo = v < o ? v : o, hi = v < o ? o : v;
                    v = keepmin ? lo : hi;
                }
            }
            if (lane < 12) sN[lane] = v;
        } else if (w == 1) {
            unsigned v = ~posCand[lane];
#pragma unroll
            for (int k = 2; k <= 64; k <<= 1) {
#pragma unroll
                for (int j = 32; j; j >>= 1) {
                    if (j >= k) continue;
                    unsigned o = __shfl_xor(v, j);
                    bool up = (lane & k) == 0;
                    bool small = (lane & j) == 0;
                    bool keepmin = (small == up);
                    unsigned lo = v < o ? v : o, hi = v < o ? o : v;
                    v = keepmin ? lo : hi;
                }
            }
            if (lane < 7) sP[lane] = ~v;
        }
    } else {
        unsigned remN = 0, remP = 0;
        for (int rd = 0; rd < 12; ++rd) {
            unsigned best = 0xFFFFFFFFu;
#pragma unroll
            for (int j = 0; j < 16; ++j) {
                int col = (j < 8) ? (t * 8 + j) : (2048 + t * 8 + (j - 8));
                unsigned b = hb[j];
                bool valid = !(b & 0x8000u) && !((remN >> j) & 1u);
                unsigned nk = valid ? ((b << 16) | (unsigned)col) : 0xFFFFFFFFu;
                best = nk < best ? nk : best;
            }
#pragma unroll
            for (int off = 32; off; off >>= 1) {
                unsigned o = __shfl_xor(best, off);
                best = o < best ? o : best;
            }
            if (lane == 0) red[w] = best;
            __syncthreads();
            if (t == 0) {
                unsigned b0 = red[0];
                b0 = red[1] < b0 ? red[1] : b0;
                b0 = red[2] < b0 ? red[2] : b0;
                b0 = red[3] < b0 ? red[3] : b0;
                sN[rd] = b0; bcast = b0;
            }
            __syncthreads();
            unsigned b0 = bcast;
#pragma unroll
            for (int j = 0; j < 16; ++j) {
                int col = (j < 8) ? (t * 8 + j) : (2048 + t * 8 + (j - 8));
                if ((((unsigned)hb[j] << 16) | (unsigned)col) == b0) remN |= 1u << j;
            }
            __syncthreads();
        }
        for (int rd = 0; rd < 7; ++rd) {
            unsigned best = 0u;
#pragma unroll
            for (int j = 0; j < 16; ++j) {
                int col = (j < 8) ? (t * 8 + j) : (2048 + t * 8 + (j - 8));
                unsigned b = hb[j];
                bool valid = (b & 0x8000u) && !((remP >> j) & 1u);
                unsigned pk = valid ? ((b << 16) | (unsigned)(N_ROWS - 1 - col)) : 0u;
                best = pk > best ? pk : best;
            }
#pragma unroll
            for (int off = 32; off; off >>= 1) {
                unsigned o = __shfl_xor(best, off);
                best = o > best ? o : best;
            }
            if (lane == 0) red[w] = best;
            __syncthreads();
            if (t == 0) {
                unsigned b0 = red[0];
                b0 = red[1] > b0 ? red[1] : b0;
                b0 = red[2] > b0 ? red[2] : b0;
                b0 = red[3] > b0 ? red[3] : b0;
                sP[rd] = b0; bcast = b0;
            }
            __syncthreads();
            unsigned b0 = bcast;
#pragma unroll
            for (int j = 0; j < 16; ++j) {
                int col = (j < 8) ? (t * 8 + j) : (2048 + t * 8 + (j - 8));
                if ((((unsigned)hb[j] << 16) | (unsigned)(N_ROWS - 1 - col)) == b0) remP |= 1u << j;
            }
            __syncthreads();
        }
    }
    __syncthreads();

    if (w == 0) {
        float thr = *thr_p;
        int tr = targets[r];
        unsigned kN = (lane < 12) ? sN[lane] : 0xFFFFFFFFu;
        unsigned kP = (lane >= 32 && lane < 39) ? sP[lane - 32] : 0u;
        int idxN = (int)(kN & 0xFFFFu) & (N_ROWS - 1);
        int idxP = (N_ROWS - 1 - (int)(kP & 0xFFFFu)) & (N_ROWS - 1);
        bool confN = (lane < 12) && kN != 0xFFFFFFFFu && (prob[idxN] >= thr);
        bool confP = (lane >= 32 && lane < 39) && kP != 0u && (prob[idxP] >= thr);
        u64 balN = __ballot(confN);
        u64 balP = __ballot(confP);

        u64 mN_ = balN & 0x7FEull;
        int selN = mN_ ? (__ffsll(mN_) - 1) : 11;
        unsigned dnn_b = __shfl(kN >> 16, selN);
        u64 mP_ = balP & (0x3Eull << 32);
        int selP = mP_ ? (__ffsll(mP_) - 1) : 38;
        unsigned dnp_b = __shfl(kP >> 16, selP);
        unsigned dap_b = __shfl(kP >> 16, 32);

        if (lane == 0) {
            auto h2f = [](unsigned b16) -> float {
                unsigned short us = (unsigned short)(b16 & 0x7FFFu);
                _Float16 h = __builtin_bit_cast(_Float16, us);
                return (float)h;
            };
            float d_ap = sqrtf(h2f(dap_b));
            float d_an = sqrtf(h2f(kN >> 16));
            int hn = idxN;
            bool cp = (balP >> 32) & 1ull;
            bool cn = balN & 1ull;
            bool fn = (pred_cls[hn] == tr);
            float d_nn = sqrtf(h2f(dnn_b));
            float d_np = sqrtf(h2f(dnp_b));

            float e1p = __expf(d_ap), e2p = __expf(d_an);
            float w1 = (e1p * d_ap + e2p * d_an) / (e1p + e2p);
            float e1n = __expf(-d_ap), e2n = __expf(-d_an);
            float w0 = (e1n * d_ap + e2n * d_an) / (e1n + e2n + 1e-6f);
            bool case_b = cp && !cn && fn;
            bool case_cd = !cp && (cn || !fn);
            bool inv = !cp && !cn && fn;
            float ap = case_b ? w1 : (case_cd ? d_np : d_ap);
            float an = case_b ? d_nn : (case_cd ? w0 : d_an);
            float per = inv ? fmaxf(an - ap + MARGIN_F, 0.f)
                            : fmaxf(ap - an + MARGIN_F, 0.f);
            per_term[r] = per;
            corr_flag[r] = (an >= ap) ? 1 : 0;
        }
    }
}

// ---------------- final deterministic reduction ----------------
__global__ __launch_bounds__(256) void finalize_kernel(
    const float* __restrict__ per_term, const int* __restrict__ corr_flag,
    const float* __restrict__ prob, const float* __restrict__ thr_p,
    float* __restrict__ out)
{
    __shared__ float sred[4]; __shared__ int cred[4]; __shared__ int nred[4];
    float thr = *thr_p;
    int t = threadIdx.x, lane = t & 63, wid = t >> 6;
    float s = 0.f; int c = 0, n = 0;
    for (int i = t; i < N_ROWS; i += 256) {
        if (prob[i] >= thr) {
            s += per_term[i];
            c += corr_flag[i];
            n += 1;
        }
    }
#pragma unroll
    for (int off = 32; off; off >>= 1) {
        s += __shfl_xor(s, off);
        c += __shfl_xor(c, off);
        n += __shfl_xor(n, off);
    }
    if (lane == 0) { sred[wid] = s; cred[wid] = c; nred[wid] = n; }
    __syncthreads();
    if (t == 0) {
        float ss = sred[0] + sred[1] + sred[2] + sred[3];
        int cc = cred[0] + cred[1] + cred[2] + cred[3];
        int nn = nred[0] + nred[1] + nred[2] + nred[3];
        float loss = (nn > 0) ? ss / (float)nn : 0.f;
        out[0] = loss;
        out[1] = (float)cc;
        out[2] = (float)nn;
    }
}

// ---------------- launch ----------------
extern "C" void kernel_launch(void* const* d_in, const int* in_sizes, int n_in,
                              void* d_out, int out_size, void* d_ws, size_t ws_size,
                              hipStream_t stream)
{
    const float* inputs     = (const float*)d_in[0];
    const float* prediction = (const float*)d_in[1];
    const int*   targets    = (const int*)d_in[2];
    const float* prob       = (const float*)d_in[4];
    const float* thr        = (const float*)d_in[5];
    float* out = (float*)d_out;

    char* ws = (char*)d_ws;
    size_t off = 0;
    auto alloc = [&](size_t bytes) -> char* {
        char* p = ws + off;
        off = (off + bytes + 255) & ~(size_t)255;
        return p;
    };
    _Float16* xh     = (_Float16*)alloc((size_t)N_ROWS * DIM * sizeof(_Float16));
    float* sq        = (float*)alloc((size_t)N_ROWS * 4);
    int*   pred_cls  = (int*)alloc((size_t)N_ROWS * 4);
    float* per_term  = (float*)alloc((size_t)N_ROWS * 4);
    int*   corr_flag = (int*)alloc((size_t)N_ROWS * 4);

    size_t avail = (ws_size > off) ? (ws_size - off) : 0;
    size_t rowbytes = (size_t)N_ROWS * 2;   // f16 dotbuf
    int RB = 128;
    while (RB * 2 <= N_ROWS && (size_t)(RB * 2) * rowbytes <= avail) RB *= 2;
    unsigned short* dotbuf = (unsigned short*)alloc((size_t)RB * rowbytes);

    hipLaunchKernelGGL(prep_kernel, dim3(N_ROWS / 4), dim3(256), 0, stream,
                       inputs, prediction, xh, sq, pred_cls);
    if (RB == N_ROWS) {
        hipLaunchKernelGGL(gemm_kernel, dim3(528), dim3(512), 0, stream,
                           xh, sq, targets, dotbuf, 0, 0);
        hipLaunchKernelGGL(select_kernel, dim3(N_ROWS), dim3(256), 0, stream,
                           dotbuf, targets, prob, pred_cls, thr, 0,
                           per_term, corr_flag);
    } else {
        for (int rb0 = 0; rb0 < N_ROWS; rb0 += RB) {
            hipLaunchKernelGGL(gemm_kernel, dim3((RB / 128) * 32), dim3(512), 0, stream,
                               xh, sq, targets, dotbuf, 1, rb0);
            hipLaunchKernelGGL(select_kernel, dim3(RB), dim3(256), 0, stream,
                               dotbuf, targets, prob, pred_cls, thr, rb0,
                               per_term, corr_flag);
        }
    }
    hipLaunchKernelGGL(finalize_kernel, dim3(1), dim3(256), 0, stream,
                       per_term, corr_flag, prob, thr, out);
}

// Round 17
// 70.254 us; speedup vs baseline: 1.1000x; 1.1000x over previous
//
#include <hip/hip_runtime.h>
#include <hip/hip_bf16.h>
#include <stdint.h>

typedef _Float16 half8 __attribute__((ext_vector_type(8)));
typedef _Float16 half4 __attribute__((ext_vector_type(4)));
typedef float f32x4 __attribute__((ext_vector_type(4)));
typedef unsigned short ushort8v __attribute__((ext_vector_type(8)));
typedef unsigned short ushort4v __attribute__((ext_vector_type(4)));
typedef unsigned long long u64;

#define N_ROWS 4096
#define DIM 1024
#define KCLS 32
#define MARGIN_F 0.3f

// ---------------- global -> LDS direct staging (16B per lane) ----------------
typedef const __attribute__((address_space(1))) void GASV;
typedef __attribute__((address_space(3))) void LASV;

__device__ __forceinline__ void gload_lds16(const void* g, void* l) {
    __builtin_amdgcn_global_load_lds((GASV*)g, (LASV*)l, 16, 0, 0);
}

// ---------------- prep: sq, f16 convert, prediction argmax ----------------
__global__ __launch_bounds__(256) void prep_kernel(
    const float* __restrict__ inputs, const float* __restrict__ prediction,
    _Float16* __restrict__ xh, float* __restrict__ sq, int* __restrict__ pred_cls)
{
    int wid = threadIdx.x >> 6, lane = threadIdx.x & 63;
    int r = blockIdx.x * 4 + wid;
    const float* row = inputs + (size_t)r * DIM;
    _Float16* hrow = xh + (size_t)r * DIM;
    float s = 0.f;
#pragma unroll
    for (int c = 0; c < 4; ++c) {
        int idx = lane * 4 + c * 256;
        float4 v = *(const float4*)(row + idx);
        s += v.x * v.x + v.y * v.y + v.z * v.z + v.w * v.w;
        half4 h;
        h.x = (_Float16)v.x; h.y = (_Float16)v.y;
        h.z = (_Float16)v.z; h.w = (_Float16)v.w;
        *(half4*)(hrow + idx) = h;
    }
#pragma unroll
    for (int off = 32; off; off >>= 1) s += __shfl_xor(s, off);

    u64 key = 0ull;
    if (lane < KCLS) {
        unsigned b = __float_as_uint(prediction[(size_t)r * KCLS + lane]);
        unsigned u = (b & 0x80000000u) ? ~b : (b | 0x80000000u);
        key = ((u64)u << 32) | (unsigned)(KCLS - 1 - lane);
    }
#pragma unroll
    for (int off = 32; off; off >>= 1) {
        u64 o = __shfl_xor(key, off);
        if (o > key) key = o;
    }
    if (lane == 0) {
        sq[r] = s;
        pred_cls[r] = KCLS - 1 - (int)(key & 0xFFFFFFFFu);
    }
}

// ---------------- f16 MFMA GEMM -> f16 d^2 (flag in sign bit), triangle 128x128 ----------------
// Counted-vmcnt double-buffered pipeline (T4): prefetch stays in flight across raw
// s_barrier; per-K-step waits only on its own buffer's 4 loads (vmcnt(4)).
// mode 0: 528 blocks = {(bx,by): bx<=by}; diag blocks have gB==gA (redundant B stage,
//         uniform vmcnt count); off-diag write normal + ushort4 mirror.
// Stored element (u16) = f16(clamp(sq_r+sq_c-2*dot,1e-12)) | (same-class << 15).
__global__ __launch_bounds__(512) void gemm_kernel(
    const _Float16* __restrict__ X, const float* __restrict__ sq,
    const int* __restrict__ targets,
    unsigned short* __restrict__ out, int mode, int rb0)
{
    __shared__ __align__(16) _Float16 As[2 * 128 * 64];   // 32 KB
    __shared__ __align__(16) _Float16 Bs[2 * 128 * 64];   // 32 KB
    int tid = threadIdx.x;

    int bx, by;
    bool mirror = false;
    if (mode == 0) {
        // bijective XCD swizzle over 528 = 8*66 blocks
        int u = ((int)blockIdx.x & 7) * 66 + ((int)blockIdx.x >> 3);
        int t_ = (int)((sqrtf(8.f * u + 1.f) - 1.f) * 0.5f);
        while ((t_ + 1) * (t_ + 2) / 2 <= u) ++t_;
        while (t_ * (t_ + 1) / 2 > u) --t_;
        by = t_;
        bx = u - t_ * (t_ + 1) / 2;
        mirror = (bx != by);
    } else {
        int nwg = gridDim.x;
        int q = nwg >> 3;
        int swz = ((int)blockIdx.x & 7) * q + ((int)blockIdx.x >> 3);
        int nbx = nwg / 32;
        bx = swz % nbx;
        by = swz / nbx;
    }

    int rs = tid >> 3;
    int ss = tid & 7;
    int srcslot = ss ^ (rs & 7);
    const _Float16* gA = X + (size_t)(rb0 + bx * 128 + rs) * DIM + srcslot * 8;
    const _Float16* gB = X + (size_t)(by * 128 + rs) * DIM + srcslot * 8;
    _Float16* lA = As + tid * 8;
    _Float16* lB = Bs + tid * 8;

    int wid = tid >> 6, lane = tid & 63;
    int wr = (wid >> 2) * 64, wc = (wid & 3) * 32;
    int fr = lane & 15, q4 = lane >> 4;

    f32x4 acc[4][2];
#pragma unroll
    for (int m = 0; m < 4; ++m)
#pragma unroll
        for (int n = 0; n < 2; ++n) acc[m][n] = (f32x4){0.f, 0.f, 0.f, 0.f};

    // STAGE(buf, t): 4 loads (2 A + 2 B) for K-step t
    auto STAGE = [&](int buf, int t) {
        int k0 = t * 64;
#pragma unroll
        for (int p = 0; p < 2; ++p) {
            gload_lds16(gA + k0 + (size_t)(p * 64) * DIM, lA + buf * 8192 + p * 4096);
            gload_lds16(gB + k0 + (size_t)(p * 64) * DIM, lB + buf * 8192 + p * 4096);
        }
    };
    auto COMPUTE = [&](int buf) {
        const _Float16* Ac = As + buf * 8192;
        const _Float16* Bc = Bs + buf * 8192;
#pragma unroll
        for (int ks = 0; ks < 2; ++ks) {
            half8 a[4], b[2];
#pragma unroll
            for (int m = 0; m < 4; ++m) {
                int row = wr + m * 16 + fr;
                int s = (ks * 4 + q4) ^ (row & 7);
                a[m] = *(const half8*)(Ac + row * 64 + s * 8);
            }
#pragma unroll
            for (int n = 0; n < 2; ++n) {
                int brow = wc + n * 16 + fr;
                int s = (ks * 4 + q4) ^ (brow & 7);
                b[n] = *(const half8*)(Bc + brow * 64 + s * 8);
            }
#pragma unroll
            for (int m = 0; m < 4; ++m)
#pragma unroll
                for (int n = 0; n < 2; ++n)
                    acc[m][n] = __builtin_amdgcn_mfma_f32_16x16x32_f16(a[m], b[n], acc[m][n], 0, 0, 0);
        }
    };

    // prologue: stage K-steps 0 and 1 (8 loads outstanding)
    STAGE(0, 0);
    STAGE(1, 1);

    int cur = 0;
    for (int t = 0; t < 15; ++t) {
        asm volatile("s_waitcnt vmcnt(4)" ::: "memory");   // cur's 4 done; next's stay in flight
        __builtin_amdgcn_s_barrier();
        __builtin_amdgcn_sched_barrier(0);
        COMPUTE(cur);
        __builtin_amdgcn_sched_barrier(0);
        __builtin_amdgcn_s_barrier();                      // all waves done reading cur
        __builtin_amdgcn_sched_barrier(0);
        if (t + 2 < 16) STAGE(cur, t + 2);                 // refill freed buffer
        cur ^= 1;
    }
    asm volatile("s_waitcnt vmcnt(0)" ::: "memory");       // final buffer
    __builtin_amdgcn_s_barrier();
    __builtin_amdgcn_sched_barrier(0);
    COMPUTE(cur);

    // epilogue: d^2 -> f16, same-class flag in sign bit
    int rbase = rb0 + bx * 128 + wr + q4 * 4;
    float sqr_[4][4];
    int trr[4][4];
#pragma unroll
    for (int m = 0; m < 4; ++m)
#pragma unroll
        for (int q = 0; q < 4; ++q) {
            sqr_[m][q] = sq[rbase + m * 16 + q];
            trr[m][q] = targets[rbase + m * 16 + q];
        }

#pragma unroll
    for (int n = 0; n < 2; ++n) {
        int col = by * 128 + wc + n * 16 + fr;
        float sqc = sq[col];
        int tc = targets[col];
#pragma unroll
        for (int m = 0; m < 4; ++m) {
            int row0 = rbase + m * 16;
            ushort4v hv;
#pragma unroll
            for (int q = 0; q < 4; ++q) {
                float d2v = fmaxf(sqr_[m][q] + sqc - 2.f * acc[m][n][q], 1e-12f);
                _Float16 h = (_Float16)d2v;
                unsigned short hb = __builtin_bit_cast(unsigned short, h);
                hb = (unsigned short)(hb | ((trr[m][q] == tc) ? 0x8000u : 0u));
                hv[q] = hb;
                out[(size_t)(row0 + q) * N_ROWS + col] = hb;
            }
            if (mirror)
                *(ushort4v*)&out[(size_t)col * N_ROWS + row0] = hv;
        }
    }
}

// ---------------- per-row selection: u16 scan + u32 prune/bitonic top-k ----------------
__global__ __launch_bounds__(256) void select_kernel(
    const unsigned short* __restrict__ dot,
    const int* __restrict__ targets, const float* __restrict__ prob,
    const int* __restrict__ pred_cls, const float* __restrict__ thr_p,
    int rb0, float* __restrict__ per_term, int* __restrict__ corr_flag)
{
    __shared__ unsigned Tn[4], Tp[4];
    __shared__ unsigned negCand[64];
    __shared__ unsigned posCand[64];
    __shared__ unsigned cnts[2];
    __shared__ unsigned sN[12], sP[7];
    __shared__ unsigned red[4];
    __shared__ unsigned bcast;

    int t = threadIdx.x, lane = t & 63, w = t >> 6;
    int rloc = blockIdx.x, r = rb0 + rloc;
    const unsigned short* drow = dot + (size_t)rloc * N_ROWS;

    if (t < 64) { negCand[t] = 0xFFFFFFFFu; posCand[t] = 0u; }
    if (t < 2) cnts[t] = 0u;

    unsigned short hb[16];
    unsigned mneg = 0xFFFFFFFFu, mpos = 0u;
    {
        ushort8v v0 = *(const ushort8v*)(drow + t * 8);
        ushort8v v1 = *(const ushort8v*)(drow + 2048 + t * 8);
#pragma unroll
        for (int j = 0; j < 8; ++j) {
            unsigned b = v0[j]; hb[j] = (unsigned short)b;
            if (b & 0x8000u) mpos = mpos > b ? mpos : b; else mneg = mneg < b ? mneg : b;
        }
#pragma unroll
        for (int j = 0; j < 8; ++j) {
            unsigned b = v1[j]; hb[8 + j] = (unsigned short)b;
            if (b & 0x8000u) mpos = mpos > b ? mpos : b; else mneg = mneg < b ? mneg : b;
        }
    }

    unsigned T3 = 0xFFFFFFFFu, m = mneg;
#pragma unroll
    for (int rd = 0; rd < 3; ++rd) {
        unsigned b = m;
#pragma unroll
        for (int off = 32; off; off >>= 1) {
            unsigned o = __shfl_xor(b, off);
            b = o < b ? o : b;
        }
        T3 = b;
        if (m == b) m = 0xFFFFFFFFu;
    }
    unsigned P2 = 0u, mp = mpos;
#pragma unroll
    for (int rd = 0; rd < 2; ++rd) {
        unsigned b = mp;
#pragma unroll
        for (int off = 32; off; off >>= 1) {
            unsigned o = __shfl_xor(b, off);
            b = o > b ? o : b;
        }
        P2 = b;
        if (mp == b) mp = 0u;
    }
    if (lane == 0) { Tn[w] = T3; Tp[w] = P2; }
    __syncthreads();

    unsigned TnB = Tn[0];
    TnB = Tn[1] > TnB ? Tn[1] : TnB;
    TnB = Tn[2] > TnB ? Tn[2] : TnB;
    TnB = Tn[3] > TnB ? Tn[3] : TnB;
    unsigned TpB = Tp[0];
    TpB = Tp[1] < TpB ? Tp[1] : TpB;
    TpB = Tp[2] < TpB ? Tp[2] : TpB;
    TpB = Tp[3] < TpB ? Tp[3] : TpB;

#pragma unroll
    for (int j = 0; j < 16; ++j) {
        int col = (j < 8) ? (t * 8 + j) : (2048 + t * 8 + (j - 8));
        unsigned b = hb[j];
        if (!(b & 0x8000u) && b <= TnB) {
            unsigned s = atomicAdd(&cnts[0], 1u);
            if (s < 64u) negCand[s] = (b << 16) | (unsigned)col;
        }
        if ((b & 0x8000u) && b >= TpB) {
            unsigned s = atomicAdd(&cnts[1], 1u);
            if (s < 64u) posCand[s] = (b << 16) | (unsigned)(N_ROWS - 1 - col);
        }
    }
    __syncthreads();

    bool fb = (cnts[0] > 64u) || (cnts[1] > 64u);

    if (!fb) {
        if (w == 0) {
            unsigned v = negCand[lane];
#pragma unroll
            for (int k = 2; k <= 64; k <<= 1) {
#pragma unroll
                for (int j = 32; j; j >>= 1) {
                    if (j >= k) continue;
                    unsigned o = __shfl_xor(v, j);
                    bool up = (lane & k) == 0;
                    bool small = (lane & j) == 0;
                    bool keepmin = (small == up);
                    unsigned lo = v < o ? v : o, hi = v < o ? o : v;
                    v = keepmin ? lo : hi;
                }
            }
            if (lane < 12) sN[lane] = v;
        } else if (w == 1) {
            unsigned v = ~posCand[lane];
#pragma unroll
            for (int k = 2; k <= 64; k <<= 1) {
#pragma unroll
                for (int j = 32; j; j >>= 1) {
                    if (j >= k) continue;
                    unsigned o = __shfl_xor(v, j);
                    bool up = (lane & k) == 0;
                    bool small = (lane & j) == 0;
                    bool keepmin = (small == up);
                    unsigned lo = v < o ? v : o, hi = v < o ? o : v;
                    v = keepmin ? lo : hi;
                }
            }
            if (lane < 7) sP[lane] = ~v;
        }
    } else {
        unsigned remN = 0, remP = 0;
        for (int rd = 0; rd < 12; ++rd) {
            unsigned best = 0xFFFFFFFFu;
#pragma unroll
            for (int j = 0; j < 16; ++j) {
                int col = (j < 8) ? (t * 8 + j) : (2048 + t * 8 + (j - 8));
                unsigned b = hb[j];
                bool valid = !(b & 0x8000u) && !((remN >> j) & 1u);
                unsigned nk = valid ? ((b << 16) | (unsigned)col) : 0xFFFFFFFFu;
                best = nk < best ? nk : best;
            }
#pragma unroll
            for (int off = 32; off; off >>= 1) {
                unsigned o = __shfl_xor(best, off);
                best = o < best ? o : best;
            }
            if (lane == 0) red[w] = best;
            __syncthreads();
            if (t == 0) {
                unsigned b0 = red[0];
                b0 = red[1] < b0 ? red[1] : b0;
                b0 = red[2] < b0 ? red[2] : b0;
                b0 = red[3] < b0 ? red[3] : b0;
                sN[rd] = b0; bcast = b0;
            }
            __syncthreads();
            unsigned b0 = bcast;
#pragma unroll
            for (int j = 0; j < 16; ++j) {
                int col = (j < 8) ? (t * 8 + j) : (2048 + t * 8 + (j - 8));
                if ((((unsigned)hb[j] << 16) | (unsigned)col) == b0) remN |= 1u << j;
            }
            __syncthreads();
        }
        for (int rd = 0; rd < 7; ++rd) {
            unsigned best = 0u;
#pragma unroll
            for (int j = 0; j < 16; ++j) {
                int col = (j < 8) ? (t * 8 + j) : (2048 + t * 8 + (j - 8));
                unsigned b = hb[j];
                bool valid = (b & 0x8000u) && !((remP >> j) & 1u);
                unsigned pk = valid ? ((b << 16) | (unsigned)(N_ROWS - 1 - col)) : 0u;
                best = pk > best ? pk : best;
            }
#pragma unroll
            for (int off = 32; off; off >>= 1) {
                unsigned o = __shfl_xor(best, off);
                best = o > best ? o : best;
            }
            if (lane == 0) red[w] = best;
            __syncthreads();
            if (t == 0) {
                unsigned b0 = red[0];
                b0 = red[1] > b0 ? red[1] : b0;
                b0 = red[2] > b0 ? red[2] : b0;
                b0 = red[3] > b0 ? red[3] : b0;
                sP[rd] = b0; bcast = b0;
            }
            __syncthreads();
            unsigned b0 = bcast;
#pragma unroll
            for (int j = 0; j < 16; ++j) {
                int col = (j < 8) ? (t * 8 + j) : (2048 + t * 8 + (j - 8));
                if ((((unsigned)hb[j] << 16) | (unsigned)(N_ROWS - 1 - col)) == b0) remP |= 1u << j;
            }
            __syncthreads();
        }
    }
    __syncthreads();

    if (w == 0) {
        float thr = *thr_p;
        int tr = targets[r];
        unsigned kN = (lane < 12) ? sN[lane] : 0xFFFFFFFFu;
        unsigned kP = (lane >= 32 && lane < 39) ? sP[lane - 32] : 0u;
        int idxN = (int)(kN & 0xFFFFu) & (N_ROWS - 1);
        int idxP = (N_ROWS - 1 - (int)(kP & 0xFFFFu)) & (N_ROWS - 1);
        bool confN = (lane < 12) && kN != 0xFFFFFFFFu && (prob[idxN] >= thr);
        bool confP = (lane >= 32 && lane < 39) && kP != 0u && (prob[idxP] >= thr);
        u64 balN = __ballot(confN);
        u64 balP = __ballot(confP);

        u64 mN_ = balN & 0x7FEull;
        int selN = mN_ ? (__ffsll(mN_) - 1) : 11;
        unsigned dnn_b = __shfl(kN >> 16, selN);
        u64 mP_ = balP & (0x3Eull << 32);
        int selP = mP_ ? (__ffsll(mP_) - 1) : 38;
        unsigned dnp_b = __shfl(kP >> 16, selP);
        unsigned dap_b = __shfl(kP >> 16, 32);

        if (lane == 0) {
            auto h2f = [](unsigned b16) -> float {
                unsigned short us = (unsigned short)(b16 & 0x7FFFu);
                _Float16 h = __builtin_bit_cast(_Float16, us);
                return (float)h;
            };
            float d_ap = sqrtf(h2f(dap_b));
            float d_an = sqrtf(h2f(kN >> 16));
            int hn = idxN;
            bool cp = (balP >> 32) & 1ull;
            bool cn = balN & 1ull;
            bool fn = (pred_cls[hn] == tr);
            float d_nn = sqrtf(h2f(dnn_b));
            float d_np = sqrtf(h2f(dnp_b));

            float e1p = __expf(d_ap), e2p = __expf(d_an);
            float w1 = (e1p * d_ap + e2p * d_an) / (e1p + e2p);
            float e1n = __expf(-d_ap), e2n = __expf(-d_an);
            float w0 = (e1n * d_ap + e2n * d_an) / (e1n + e2n + 1e-6f);
            bool case_b = cp && !cn && fn;
            bool case_cd = !cp && (cn || !fn);
            bool inv = !cp && !cn && fn;
            float ap = case_b ? w1 : (case_cd ? d_np : d_ap);
            float an = case_b ? d_nn : (case_cd ? w0 : d_an);
            float per = inv ? fmaxf(an - ap + MARGIN_F, 0.f)
                            : fmaxf(ap - an + MARGIN_F, 0.f);
            per_term[r] = per;
            corr_flag[r] = (an >= ap) ? 1 : 0;
        }
    }
}

// ---------------- final deterministic reduction ----------------
__global__ __launch_bounds__(256) void finalize_kernel(
    const float* __restrict__ per_term, const int* __restrict__ corr_flag,
    const float* __restrict__ prob, const float* __restrict__ thr_p,
    float* __restrict__ out)
{
    __shared__ float sred[4]; __shared__ int cred[4]; __shared__ int nred[4];
    float thr = *thr_p;
    int t = threadIdx.x, lane = t & 63, wid = t >> 6;
    float s = 0.f; int c = 0, n = 0;
    for (int i = t; i < N_ROWS; i += 256) {
        if (prob[i] >= thr) {
            s += per_term[i];
            c += corr_flag[i];
            n += 1;
        }
    }
#pragma unroll
    for (int off = 32; off; off >>= 1) {
        s += __shfl_xor(s, off);
        c += __shfl_xor(c, off);
        n += __shfl_xor(n, off);
    }
    if (lane == 0) { sred[wid] = s; cred[wid] = c; nred[wid] = n; }
    __syncthreads();
    if (t == 0) {
        float ss = sred[0] + sred[1] + sred[2] + sred[3];
        int cc = cred[0] + cred[1] + cred[2] + cred[3];
        int nn = nred[0] + nred[1] + nred[2] + nred[3];
        float loss = (nn > 0) ? ss / (float)nn : 0.f;
        out[0] = loss;
        out[1] = (float)cc;
        out[2] = (float)nn;
    }
}

// ---------------- launch ----------------
extern "C" void kernel_launch(void* const* d_in, const int* in_sizes, int n_in,
                              void* d_out, int out_size, void* d_ws, size_t ws_size,
                              hipStream_t stream)
{
    const float* inputs     = (const float*)d_in[0];
    const float* prediction = (const float*)d_in[1];
    const int*   targets    = (const int*)d_in[2];
    const float* prob       = (const float*)d_in[4];
    const float* thr        = (const float*)d_in[5];
    float* out = (float*)d_out;

    char* ws = (char*)d_ws;
    size_t off = 0;
    auto alloc = [&](size_t bytes) -> char* {
        char* p = ws + off;
        off = (off + bytes + 255) & ~(size_t)255;
        return p;
    };
    _Float16* xh     = (_Float16*)alloc((size_t)N_ROWS * DIM * sizeof(_Float16));
    float* sq        = (float*)alloc((size_t)N_ROWS * 4);
    int*   pred_cls  = (int*)alloc((size_t)N_ROWS * 4);
    float* per_term  = (float*)alloc((size_t)N_ROWS * 4);
    int*   corr_flag = (int*)alloc((size_t)N_ROWS * 4);

    size_t avail = (ws_size > off) ? (ws_size - off) : 0;
    size_t rowbytes = (size_t)N_ROWS * 2;   // f16 dotbuf
    int RB = 128;
    while (RB * 2 <= N_ROWS && (size_t)(RB * 2) * rowbytes <= avail) RB *= 2;
    unsigned short* dotbuf = (unsigned short*)alloc((size_t)RB * rowbytes);

    hipLaunchKernelGGL(prep_kernel, dim3(N_ROWS / 4), dim3(256), 0, stream,
                       inputs, prediction, xh, sq, pred_cls);
    if (RB == N_ROWS) {
        hipLaunchKernelGGL(gemm_kernel, dim3(528), dim3(512), 0, stream,
                           xh, sq, targets, dotbuf, 0, 0);
        hipLaunchKernelGGL(select_kernel, dim3(N_ROWS), dim3(256), 0, stream,
                           dotbuf, targets, prob, pred_cls, thr, 0,
                           per_term, corr_flag);
    } else {
        for (int rb0 = 0; rb0 < N_ROWS; rb0 += RB) {
            hipLaunchKernelGGL(gemm_kernel, dim3((RB / 128) * 32), dim3(512), 0, stream,
                               xh, sq, targets, dotbuf, 1, rb0);
            hipLaunchKernelGGL(select_kernel, dim3(RB), dim3(256), 0, stream,
                               dotbuf, targets, prob, pred_cls, thr, rb0,
                               per_term, corr_flag);
        }
    }
    hipLaunchKernelGGL(finalize_kernel, dim3(1), dim3(256), 0, stream,
                       per_term, corr_flag, prob, thr, out);
}